// Round 1
// baseline (1787.645 us; speedup 1.0000x reference)
//
#include <hip/hip_runtime.h>
#include <hip/hip_bf16.h>
#include <cstddef>

#define B_ 2
#define F_ 2048
#define D_ 1024
#define H_ 16
#define DK_ 64
#define BF_ (B_ * F_)   // 4096

// GEMM tiling: 128x64 tile, 256 threads, 8x4 microtile
#define BM 128
#define BN 64
#define BK 16
#define TM 8
#define TN 4

// C[M][N] = A[M][K] @ W[N][K]^T + bias[N]
__global__ __launch_bounds__(256) void gemm_xwt(
    const float* __restrict__ A, const float* __restrict__ W,
    const float* __restrict__ bias, float* __restrict__ C,
    int M, int N, int K) {
  __shared__ float As[BK][BM + 4];
  __shared__ float Bs[BK][BN + 4];
  const int tid = threadIdx.x;
  const int tx = tid & 15, ty = tid >> 4;
  const int m0 = blockIdx.y * BM, n0 = blockIdx.x * BN;
  const int ar = tid >> 2, ac = (tid & 3) * 4;
  float acc[TM][TN] = {};
  for (int k0 = 0; k0 < K; k0 += BK) {
    const float4 a0 = *(const float4*)&A[(size_t)(m0 + ar) * K + k0 + ac];
    const float4 a1 = *(const float4*)&A[(size_t)(m0 + ar + 64) * K + k0 + ac];
    const float4 w0 = *(const float4*)&W[(size_t)(n0 + ar) * K + k0 + ac];
    __syncthreads();
    As[ac + 0][ar] = a0.x; As[ac + 1][ar] = a0.y;
    As[ac + 2][ar] = a0.z; As[ac + 3][ar] = a0.w;
    As[ac + 0][ar + 64] = a1.x; As[ac + 1][ar + 64] = a1.y;
    As[ac + 2][ar + 64] = a1.z; As[ac + 3][ar + 64] = a1.w;
    Bs[ac + 0][ar] = w0.x; Bs[ac + 1][ar] = w0.y;
    Bs[ac + 2][ar] = w0.z; Bs[ac + 3][ar] = w0.w;
    __syncthreads();
#pragma unroll
    for (int kk = 0; kk < BK; ++kk) {
      float a[TM], b[TN];
      *(float4*)&a[0] = *(const float4*)&As[kk][ty * TM];
      *(float4*)&a[4] = *(const float4*)&As[kk][ty * TM + 4];
      *(float4*)&b[0] = *(const float4*)&Bs[kk][tx * TN];
#pragma unroll
      for (int i = 0; i < TM; ++i)
#pragma unroll
        for (int j = 0; j < TN; ++j)
          acc[i][j] = fmaf(a[i], b[j], acc[i][j]);
    }
  }
  const int col = n0 + tx * TN;
  const float4 bv = *(const float4*)&bias[col];
#pragma unroll
  for (int i = 0; i < TM; ++i) {
    const int row = m0 + ty * TM + i;
    float4 r;
    r.x = acc[i][0] + bv.x;
    r.y = acc[i][1] + bv.y;
    r.z = acc[i][2] + bv.z;
    r.w = acc[i][3] + bv.w;
    *(float4*)&C[(size_t)row * N + col] = r;
  }
}

// Unnormalized exp(Q_h K_h^T / 32) per (b,h) -> attn region
__global__ __launch_bounds__(256) void scores_exp(
    const float* __restrict__ Qp, const float* __restrict__ Kp,
    float* __restrict__ attn) {
  const int bh = blockIdx.z;
  const int b = bh >> 4, h = bh & 15;
  const float* Aq = Qp + (size_t)b * F_ * D_ + h * DK_;
  const float* Ak = Kp + (size_t)b * F_ * D_ + h * DK_;
  float* O = attn + (size_t)bh * F_ * F_;
  __shared__ float As[BK][BM + 4];
  __shared__ float Bs[BK][BN + 4];
  const int tid = threadIdx.x;
  const int tx = tid & 15, ty = tid >> 4;
  const int m0 = blockIdx.y * BM, n0 = blockIdx.x * BN;
  const int ar = tid >> 2, ac = (tid & 3) * 4;
  float acc[TM][TN] = {};
#pragma unroll
  for (int k0 = 0; k0 < DK_; k0 += BK) {
    const float4 a0 = *(const float4*)&Aq[(size_t)(m0 + ar) * D_ + k0 + ac];
    const float4 a1 = *(const float4*)&Aq[(size_t)(m0 + ar + 64) * D_ + k0 + ac];
    const float4 w0 = *(const float4*)&Ak[(size_t)(n0 + ar) * D_ + k0 + ac];
    __syncthreads();
    As[ac + 0][ar] = a0.x; As[ac + 1][ar] = a0.y;
    As[ac + 2][ar] = a0.z; As[ac + 3][ar] = a0.w;
    As[ac + 0][ar + 64] = a1.x; As[ac + 1][ar + 64] = a1.y;
    As[ac + 2][ar + 64] = a1.z; As[ac + 3][ar + 64] = a1.w;
    Bs[ac + 0][ar] = w0.x; Bs[ac + 1][ar] = w0.y;
    Bs[ac + 2][ar] = w0.z; Bs[ac + 3][ar] = w0.w;
    __syncthreads();
#pragma unroll
    for (int kk = 0; kk < BK; ++kk) {
      float a[TM], b[TN];
      *(float4*)&a[0] = *(const float4*)&As[kk][ty * TM];
      *(float4*)&a[4] = *(const float4*)&As[kk][ty * TM + 4];
      *(float4*)&b[0] = *(const float4*)&Bs[kk][tx * TN];
#pragma unroll
      for (int i = 0; i < TM; ++i)
#pragma unroll
        for (int j = 0; j < TN; ++j)
          acc[i][j] = fmaf(a[i], b[j], acc[i][j]);
    }
  }
  const int col = n0 + tx * TN;
#pragma unroll
  for (int i = 0; i < TM; ++i) {
    const int row = m0 + ty * TM + i;
    float4 r;
    r.x = __expf(acc[i][0] * 0.03125f);
    r.y = __expf(acc[i][1] * 0.03125f);
    r.z = __expf(acc[i][2] * 0.03125f);
    r.w = __expf(acc[i][3] * 0.03125f);
    *(float4*)&O[(size_t)row * F_ + col] = r;
  }
}

// Softmax over the HEADS axis: attn[b,h,q,k] /= sum_h' attn[b,h',q,k]
__global__ __launch_bounds__(256) void softmax_heads(float* __restrict__ attn) {
  const int bq = blockIdx.x;             // b*F + q
  const int b = bq >> 11, q = bq & (F_ - 1);
  const size_t base = (size_t)b * H_ * F_ * F_ + (size_t)q * F_;
  const size_t hs = (size_t)F_ * F_;
#pragma unroll
  for (int c = 0; c < F_ / 256; ++c) {
    const int k = c * 256 + threadIdx.x;
    float v[H_];
    float s = 0.f;
#pragma unroll
    for (int h = 0; h < H_; ++h) {
      v[h] = attn[base + (size_t)h * hs + k];
      s += v[h];
    }
    const float inv = 1.0f / s;
#pragma unroll
    for (int h = 0; h < H_; ++h)
      attn[base + (size_t)h * hs + k] = v[h] * inv;
  }
}

// res[b,h,q,dk] = sum_k attn[b,h,q,k] * Vp[b,k,h*64+dk], written into the
// scrambled layout from transpose(1,2,0,3).reshape(B,F,D):
//   i2 = (h>>3)*F + (h&7)*256 + (q>>3);  d2 = (q&7)*128 + b*64 + dk
__global__ __launch_bounds__(256) void pv_gemm(
    const float* __restrict__ attn, const float* __restrict__ Vp,
    float* __restrict__ resS) {
  const int bh = blockIdx.z;
  const int b = bh >> 4, h = bh & 15;
  const float* Aa = attn + (size_t)bh * F_ * F_;           // [F][F]
  const float* Vb = Vp + (size_t)b * F_ * D_ + h * DK_;    // rows k (stride D_)
  __shared__ float As[BK][BM + 4];
  __shared__ float Bs[BK][DK_ + 4];
  const int tid = threadIdx.x;
  const int tx = tid & 15, ty = tid >> 4;
  const int m0 = blockIdx.y * BM;
  const int ar = tid >> 2, ac = (tid & 3) * 4;
  const int br = tid >> 4, bc = (tid & 15) * 4;
  float acc[TM][TN] = {};
  for (int k0 = 0; k0 < F_; k0 += BK) {
    const float4 a0 = *(const float4*)&Aa[(size_t)(m0 + ar) * F_ + k0 + ac];
    const float4 a1 = *(const float4*)&Aa[(size_t)(m0 + ar + 64) * F_ + k0 + ac];
    const float4 v0 = *(const float4*)&Vb[(size_t)(k0 + br) * D_ + bc];
    __syncthreads();
    As[ac + 0][ar] = a0.x; As[ac + 1][ar] = a0.y;
    As[ac + 2][ar] = a0.z; As[ac + 3][ar] = a0.w;
    As[ac + 0][ar + 64] = a1.x; As[ac + 1][ar + 64] = a1.y;
    As[ac + 2][ar + 64] = a1.z; As[ac + 3][ar + 64] = a1.w;
    *(float4*)&Bs[br][bc] = v0;
    __syncthreads();
#pragma unroll
    for (int kk = 0; kk < BK; ++kk) {
      float a[TM], b[TN];
      *(float4*)&a[0] = *(const float4*)&As[kk][ty * TM];
      *(float4*)&a[4] = *(const float4*)&As[kk][ty * TM + 4];
      *(float4*)&b[0] = *(const float4*)&Bs[kk][tx * TN];
#pragma unroll
      for (int i = 0; i < TM; ++i)
#pragma unroll
        for (int j = 0; j < TN; ++j)
          acc[i][j] = fmaf(a[i], b[j], acc[i][j]);
    }
  }
#pragma unroll
  for (int i = 0; i < TM; ++i) {
    const int q = m0 + ty * TM + i;
    const int i2 = (h >> 3) * F_ + (h & 7) * 256 + (q >> 3);
    const int d2 = (q & 7) * 128 + b * 64 + tx * TN;
    float4 r;
    r.x = acc[i][0]; r.y = acc[i][1]; r.z = acc[i][2]; r.w = acc[i][3];
    *(float4*)&resS[(size_t)i2 * D_ + d2] = r;
  }
}

extern "C" void kernel_launch(void* const* d_in, const int* in_sizes, int n_in,
                              void* d_out, int out_size, void* d_ws, size_t ws_size,
                              hipStream_t stream) {
  const float* k_in = (const float*)d_in[0];
  const float* q_in = (const float*)d_in[1];
  const float* v_in = (const float*)d_in[2];
  const float* Wq = (const float*)d_in[3];
  const float* bq = (const float*)d_in[4];
  const float* Wk = (const float*)d_in[5];
  const float* bk = (const float*)d_in[6];
  const float* Wv = (const float*)d_in[7];
  const float* bv = (const float*)d_in[8];
  const float* W2 = (const float*)d_in[9];
  const float* b2 = (const float*)d_in[10];

  float* out = (float*)d_out;                      // [BF_, D_]
  float* attn = out + (size_t)BF_ * D_;            // [B,H,F,F]

  float* ws = (float*)d_ws;
  float* Qp = ws;                                  // [BF_, D_]
  float* Kp = Qp + (size_t)BF_ * D_;
  float* Vp = Kp + (size_t)BF_ * D_;
  float* resS = Vp + (size_t)BF_ * D_;             // scrambled res [BF_, D_]

  const dim3 blk(256);
  const dim3 g1(D_ / BN, BF_ / BM);                // (16, 32)
  hipLaunchKernelGGL(gemm_xwt, g1, blk, 0, stream, q_in, Wq, bq, Qp, BF_, D_, D_);
  hipLaunchKernelGGL(gemm_xwt, g1, blk, 0, stream, k_in, Wk, bk, Kp, BF_, D_, D_);
  hipLaunchKernelGGL(gemm_xwt, g1, blk, 0, stream, v_in, Wv, bv, Vp, BF_, D_, D_);

  const dim3 g2(F_ / BN, F_ / BM, B_ * H_);        // (32, 16, 32)
  hipLaunchKernelGGL(scores_exp, g2, blk, 0, stream, Qp, Kp, attn);

  hipLaunchKernelGGL(softmax_heads, dim3(BF_), blk, 0, stream, attn);

  const dim3 g3(1, F_ / BM, B_ * H_);              // (1, 16, 32)
  hipLaunchKernelGGL(pv_gemm, g3, blk, 0, stream, attn, Vp, resS);

  hipLaunchKernelGGL(gemm_xwt, g1, blk, 0, stream, resS, W2, b2, out, BF_, D_, D_);
}

// Round 2
// 1167.828 us; speedup vs baseline: 1.5307x; 1.5307x over previous
//
#include <hip/hip_runtime.h>
#include <cstddef>
#include <cstdint>

#define B_ 2
#define F_ 2048
#define D_ 1024
#define H_ 16
#define DK_ 64
#define BF_ (B_*F_)

typedef __attribute__((ext_vector_type(8))) short bf16x8;     // MFMA A/B operand (8 bf16)
typedef __attribute__((ext_vector_type(4))) float f32x4;      // MFMA C/D operand
typedef __attribute__((ext_vector_type(8))) unsigned short u16x8;
typedef __attribute__((ext_vector_type(4))) unsigned short u16x4;

#define MFMA(a,b,c) __builtin_amdgcn_mfma_f32_16x16x32_bf16((a),(b),(c),0,0,0)

// fp32 -> bf16, round-to-nearest-even (exact for finite inputs)
__device__ __forceinline__ unsigned short f2bf(float f){
  unsigned u = __float_as_uint(f);
  u += 0x7fffu + ((u >> 16) & 1u);
  return (unsigned short)(u >> 16);
}
__device__ __forceinline__ float bf2f(unsigned short h){
  return __uint_as_float(((unsigned)h) << 16);
}

// ---------------------------------------------------------------------------
// Convert q,k,v,Wq,Wk,Wv,W2 (fp32) -> contiguous bf16 region at ws[0 .. 2^24)
// dst order: qb kb vb Wqb Wkb Wvb W2b. 2^24 elems total, 8 per thread.
// ---------------------------------------------------------------------------
__global__ __launch_bounds__(256) void convert_all(
    const float* __restrict__ q, const float* __restrict__ k, const float* __restrict__ v,
    const float* __restrict__ wq, const float* __restrict__ wk, const float* __restrict__ wv,
    const float* __restrict__ w2, unsigned short* __restrict__ dst){
  const size_t t = (size_t)blockIdx.x * 256 + threadIdx.x;   // 0 .. 2^21
  const size_t e = t * 8;
  const float* s; size_t off;
  if (e < 12582912) {                  // 3 x 4194304 activations
    const size_t r = e >> 22;
    s = (r == 0) ? q : (r == 1) ? k : v;
    off = e & 4194303;
  } else {                             // 4 x 1048576 weights
    const size_t e2 = e - 12582912;
    const size_t r = e2 >> 20;
    s = (r == 0) ? wq : (r == 1) ? wk : (r == 2) ? wv : w2;
    off = e2 & 1048575;
  }
  const float4 lo = *(const float4*)&s[off];
  const float4 hi = *(const float4*)&s[off + 4];
  u16x8 o;
  o[0]=f2bf(lo.x); o[1]=f2bf(lo.y); o[2]=f2bf(lo.z); o[3]=f2bf(lo.w);
  o[4]=f2bf(hi.x); o[5]=f2bf(hi.y); o[6]=f2bf(hi.z); o[7]=f2bf(hi.w);
  *(u16x8*)&dst[e] = o;
}

// ---------------------------------------------------------------------------
// C[M=4096][N=1024] = A[4096][1024] @ W[1024][1024]^T + bias
// bf16 MFMA 16x16x32, LDS-free direct fragment loads (L1/L2 reuse).
// Block 256 thr = 4 waves (2x2), block tile 128x64, wave tile 64x32.
// EPI 0: store bf16 row-major [4096][1024]
// EPI 1: store fp32 row-major
// EPI 2: store bf16 transposed to Vt[(b*1024+n)*2048 + f]  (b=row>>11, f=row&2047)
// ---------------------------------------------------------------------------
template<int EPI>
__global__ __launch_bounds__(256) void gemm_dfrag(
    const unsigned short* __restrict__ A, const unsigned short* __restrict__ W,
    const float* __restrict__ bias, void* __restrict__ Cout){
  const int K = 1024;
  const int tid = threadIdx.x, l = tid & 63, wid = tid >> 6;
  const int wm = wid >> 1, wn = wid & 1;
  const int m0 = blockIdx.y * 128 + wm * 64;
  const int n0 = blockIdx.x * 64 + wn * 32;
  const int lr = l & 15, lk = (l >> 4) << 3;
  f32x4 acc[4][2] = {};
#pragma unroll 2
  for (int k0 = 0; k0 < K; k0 += 32) {
    bf16x8 a[4], b[2];
#pragma unroll
    for (int mi = 0; mi < 4; ++mi)
      a[mi] = *(const bf16x8*)&A[(size_t)(m0 + mi*16 + lr)*K + k0 + lk];
#pragma unroll
    for (int ni = 0; ni < 2; ++ni)
      b[ni] = *(const bf16x8*)&W[(size_t)(n0 + ni*16 + lr)*K + k0 + lk];
#pragma unroll
    for (int mi = 0; mi < 4; ++mi)
#pragma unroll
      for (int ni = 0; ni < 2; ++ni)
        acc[mi][ni] = MFMA(a[mi], b[ni], acc[mi][ni]);
  }
#pragma unroll
  for (int ni = 0; ni < 2; ++ni) {
    const int n = n0 + ni*16 + lr;
    const float bv = bias[n];
#pragma unroll
    for (int mi = 0; mi < 4; ++mi) {
      const int mb = m0 + mi*16 + (l >> 4)*4;     // 4 consecutive rows
      if (EPI == 0) {
        unsigned short* C = (unsigned short*)Cout;
#pragma unroll
        for (int r = 0; r < 4; ++r)
          C[(size_t)(mb + r)*1024 + n] = f2bf(acc[mi][ni][r] + bv);
      } else if (EPI == 1) {
        float* C = (float*)Cout;
#pragma unroll
        for (int r = 0; r < 4; ++r)
          C[(size_t)(mb + r)*1024 + n] = acc[mi][ni][r] + bv;
      } else {
        unsigned short* C = (unsigned short*)Cout;
        const int bb = mb >> 11, f0 = mb & 2047;
        u16x4 o;
        o[0]=f2bf(acc[mi][ni][0]+bv); o[1]=f2bf(acc[mi][ni][1]+bv);
        o[2]=f2bf(acc[mi][ni][2]+bv); o[3]=f2bf(acc[mi][ni][3]+bv);
        *(u16x4*)&C[((size_t)bb*1024 + n)*2048 + f0] = o;
      }
    }
  }
}

// ---------------------------------------------------------------------------
// Fused scores + softmax-over-heads.
// Wave computes a 16q x 16k microtile for ALL 16 heads (K=64 each -> 2 MFMAs).
// All 16 head values of a given (q,k) land in the SAME lane -> in-register
// normalization (sum of 16 regs), then write final attn fp32.
// Block 256 thr = 4 waves (2x2) -> 32q x 32k per block. Grid 64*64*2 linear,
// XCD-swizzled.
// ---------------------------------------------------------------------------
__global__ __launch_bounds__(256) void scores_smax(
    const unsigned short* __restrict__ Qp, const unsigned short* __restrict__ Kp,
    float* __restrict__ attn){
  const int id = blockIdx.x;
  const int sw = (id & 7) * 1024 + (id >> 3);        // bijective, 8192 % 8 == 0
  const int kt = sw & 63, qt = (sw >> 6) & 63, b = sw >> 12;
  const int l = threadIdx.x & 63, wid = threadIdx.x >> 6;
  const int q0 = qt*32 + (wid >> 1)*16;
  const int k0 = kt*32 + (wid & 1)*16;
  const int lr = l & 15, lk = (l >> 4) << 3;
  const unsigned short* Qb = Qp + (size_t)b * F_ * D_;
  const unsigned short* Kb = Kp + (size_t)b * F_ * D_;
  f32x4 acc[16];
#pragma unroll
  for (int h = 0; h < 16; ++h) {
    const bf16x8 a0 = *(const bf16x8*)&Qb[(size_t)(q0 + lr)*D_ + h*64 + lk];
    const bf16x8 a1 = *(const bf16x8*)&Qb[(size_t)(q0 + lr)*D_ + h*64 + 32 + lk];
    const bf16x8 b0 = *(const bf16x8*)&Kb[(size_t)(k0 + lr)*D_ + h*64 + lk];
    const bf16x8 b1 = *(const bf16x8*)&Kb[(size_t)(k0 + lr)*D_ + h*64 + 32 + lk];
    f32x4 z = {};
    z = MFMA(a0, b0, z);
    acc[h] = MFMA(a1, b1, z);
  }
  const float sc = 0.03125f;   // 1/sqrt(1024)
#pragma unroll
  for (int r = 0; r < 4; ++r) {
    float e[16]; float s = 0.f;
#pragma unroll
    for (int h = 0; h < 16; ++h) { e[h] = __expf(acc[h][r] * sc); s += e[h]; }
    const float inv = 1.f / s;
    const int qq = q0 + (l >> 4)*4 + r;
    const size_t rowbase = (size_t)b*16*F_*F_ + (size_t)qq*F_ + (k0 + lr);
#pragma unroll
    for (int h = 0; h < 16; ++h)
      attn[rowbase + (size_t)h*F_*F_] = e[h] * inv;
  }
}

// ---------------------------------------------------------------------------
// res[b,h,q,dk] = sum_k attn[b,h,q,k] * V[b,k,h*64+dk], via Vt[b,h*64+dk,k].
// attn read fp32, split hi/lo bf16 (2 MFMAs) for near-fp32 operand precision.
// Block 512 thr = 8 waves, wave = 16q x 64dk. Grid (16 qtiles, 32 bh).
// Store bf16 into scrambled resS layout (transpose(1,2,0,3).reshape quirk):
//   i2=(h>>3)*2048+(h&7)*256+(q>>3); d2=(q&7)*128+b*64+dk
// ---------------------------------------------------------------------------
__global__ __launch_bounds__(512) void pv_mfma(
    const float* __restrict__ attn, const unsigned short* __restrict__ Vt,
    unsigned short* __restrict__ resS){
  const int bh = blockIdx.y, b = bh >> 4, h = bh & 15;
  const int l = threadIdx.x & 63, wid = threadIdx.x >> 6;
  const int q0 = blockIdx.x * 128 + wid * 16;
  const int lr = l & 15, lk = (l >> 4) << 3;
  const float* Ab = attn + (size_t)bh * F_ * F_;
  const unsigned short* Vb = Vt + ((size_t)b * D_ + h * 64) * F_;
  f32x4 acc[4] = {};
#pragma unroll 2
  for (int k0 = 0; k0 < F_; k0 += 32) {
    const float4 af0 = *(const float4*)&Ab[(size_t)(q0 + lr)*F_ + k0 + lk];
    const float4 af1 = *(const float4*)&Ab[(size_t)(q0 + lr)*F_ + k0 + lk + 4];
    const float fa[8] = {af0.x, af0.y, af0.z, af0.w, af1.x, af1.y, af1.z, af1.w};
    bf16x8 ah, al;
#pragma unroll
    for (int j = 0; j < 8; ++j) {
      const unsigned short hb = f2bf(fa[j]);
      ah[j] = (short)hb;
      al[j] = (short)f2bf(fa[j] - bf2f(hb));   // exact residual (Sterbenz)
    }
#pragma unroll
    for (int ni = 0; ni < 4; ++ni) {
      const bf16x8 bv = *(const bf16x8*)&Vb[(size_t)(ni*16 + lr)*F_ + k0 + lk];
      acc[ni] = MFMA(ah, bv, acc[ni]);
      acc[ni] = MFMA(al, bv, acc[ni]);
    }
  }
#pragma unroll
  for (int ni = 0; ni < 4; ++ni) {
#pragma unroll
    for (int r = 0; r < 4; ++r) {
      const int q = q0 + (l >> 4)*4 + r;
      const int dk = ni*16 + lr;
      const int i2 = (h >> 3)*F_ + (h & 7)*256 + (q >> 3);
      const int d2 = (q & 7)*128 + b*64 + dk;
      resS[(size_t)i2*D_ + d2] = f2bf(acc[ni][r]);
    }
  }
}

// ---------------------------------------------------------------------------
extern "C" void kernel_launch(void* const* d_in, const int* in_sizes, int n_in,
                              void* d_out, int out_size, void* d_ws, size_t ws_size,
                              hipStream_t stream) {
  const float* k_in = (const float*)d_in[0];
  const float* q_in = (const float*)d_in[1];
  const float* v_in = (const float*)d_in[2];
  const float* Wq = (const float*)d_in[3];
  const float* bq = (const float*)d_in[4];
  const float* Wk = (const float*)d_in[5];
  const float* bk = (const float*)d_in[6];
  const float* Wv = (const float*)d_in[7];
  const float* bv = (const float*)d_in[8];
  const float* W2 = (const float*)d_in[9];
  const float* b2 = (const float*)d_in[10];

  float* out  = (float*)d_out;                       // [4096][1024]
  float* attn = out + (size_t)BF_ * D_;              // [2,16,2048,2048]

  unsigned short* ws = (unsigned short*)d_ws;        // bf16 workspace (64 MiB)
  unsigned short* qb   = ws;                         // converted activations
  unsigned short* kb   = ws + 4194304;
  unsigned short* vb   = ws + 8388608;
  unsigned short* Wqb  = ws + 12582912;              // converted weights
  unsigned short* Wkb  = ws + 13631488;
  unsigned short* Wvb  = ws + 14680064;
  unsigned short* W2b  = ws + 15728640;
  unsigned short* Qp   = ws + 16777216;              // projected Q bf16 [4096][1024]
  unsigned short* Kp   = ws + 20971520;              // projected K bf16
  unsigned short* Vt   = ws + 25165824;              // projected V transposed [2][1024][2048]
  unsigned short* resS = ws + 29360128;              // scrambled res bf16 [4096][1024]

  hipLaunchKernelGGL(convert_all, dim3(8192), dim3(256), 0, stream,
                     q_in, k_in, v_in, Wq, Wk, Wv, W2, ws);

  const dim3 gg(16, 32), gb(256);
  hipLaunchKernelGGL((gemm_dfrag<0>), gg, gb, 0, stream, qb, Wqb, bq, (void*)Qp);
  hipLaunchKernelGGL((gemm_dfrag<0>), gg, gb, 0, stream, kb, Wkb, bk, (void*)Kp);
  hipLaunchKernelGGL((gemm_dfrag<2>), gg, gb, 0, stream, vb, Wvb, bv, (void*)Vt);

  hipLaunchKernelGGL(scores_smax, dim3(8192), dim3(256), 0, stream, Qp, Kp, attn);

  hipLaunchKernelGGL(pv_mfma, dim3(16, 32), dim3(512), 0, stream, attn, Vt, resS);

  hipLaunchKernelGGL((gemm_dfrag<1>), gg, gb, 0, stream, resS, W2b, b2, (void*)out);
}